// Round 4
// baseline (1525.143 us; speedup 1.0000x reference)
//
#include <hip/hip_runtime.h>
#include <hip/hip_bf16.h>
#include <cstdint>
#include <cstddef>

#define F_IN 767
#define HD   16

// ======================= counting-sort of edges by col =======================

__global__ void k_hist(const int* __restrict__ col, int* __restrict__ cnt, int E) {
  int e = blockIdx.x * 256 + threadIdx.x;
  if (e < E) atomicAdd(&cnt[col[e]], 1);
}

// block scan: 256 threads x 4 items = 1024 items/block.
__global__ void k_scan1(const int* __restrict__ cnt, int* __restrict__ off,
                        int* __restrict__ bsum, int N) {
  __shared__ int lds[256];
  int t = threadIdx.x;
  int base = blockIdx.x * 1024 + t * 4;
  int4 v = make_int4(0, 0, 0, 0);
  if (base + 3 < N) {
    v = *(const int4*)&cnt[base];
  } else {
    if (base + 0 < N) v.x = cnt[base + 0];
    if (base + 1 < N) v.y = cnt[base + 1];
    if (base + 2 < N) v.z = cnt[base + 2];
    if (base + 3 < N) v.w = cnt[base + 3];
  }
  int s = v.x + v.y + v.z + v.w;
  lds[t] = s;
  __syncthreads();
  for (int d = 1; d < 256; d <<= 1) {
    int add = (t >= d) ? lds[t - d] : 0;
    __syncthreads();
    lds[t] += add;
    __syncthreads();
  }
  int excl = lds[t] - s;
  if (t == 255) bsum[blockIdx.x] = lds[255];
  int run = excl;
  if (base + 0 < N) off[base + 0] = run; run += v.x;
  if (base + 1 < N) off[base + 1] = run; run += v.y;
  if (base + 2 < N) off[base + 2] = run; run += v.z;
  if (base + 3 < N) off[base + 3] = run;
}

// single block: exclusive scan of block sums in place (nb <= 256)
__global__ void k_scan2(int* __restrict__ bsum, int nb) {
  __shared__ int lds[256];
  int t = threadIdx.x;
  int s = (t < nb) ? bsum[t] : 0;
  lds[t] = s;
  __syncthreads();
  for (int d = 1; d < 256; d <<= 1) {
    int add = (t >= d) ? lds[t - d] : 0;
    __syncthreads();
    lds[t] += add;
    __syncthreads();
  }
  if (t < nb) bsum[t] = lds[t] - s;
}

// finalize offsets, copy to cursor, compute dinv
__global__ void k_scan3(const int* __restrict__ cnt, int* __restrict__ off,
                        int* __restrict__ cur, float* __restrict__ dinv,
                        const int* __restrict__ bsum, int N) {
  int i = blockIdx.x * 256 + threadIdx.x;
  if (i < N) {
    int o = off[i] + bsum[i >> 10];
    off[i] = o;
    cur[i] = o;
    int c = cnt[i];
    dinv[i] = (c > 0) ? rsqrtf((float)c) : 0.f;
  }
}

__global__ void k_build(const int* __restrict__ row, const int* __restrict__ col,
                        int* __restrict__ cur, int* __restrict__ srow, int E) {
  int e = blockIdx.x * 256 + threadIdx.x;
  if (e < E) {
    int c = col[e];
    int p = atomicAdd(&cur[c], 1);
    srow[p] = row[e];
  }
}

// ======================= weight pack: f32 [wi | wr] -> f32 Wc[K][2H] =======================
__global__ void k_pack(const float* __restrict__ wi, const float* __restrict__ wr,
                       float* __restrict__ Wc, int K, int H) {
  int i = blockIdx.x * 256 + threadIdx.x;
  int tot = K * 2 * H;
  if (i < tot) {
    int k = i / (2 * H), c = i % (2 * H);
    Wc[i] = (c < H) ? wi[k * H + c] : wr[k * H + (c - H)];
  }
}

// ======================= GEMM1: x[N,767](f32) @ Wc[767,32](f32) -> T[N,32](f32) =======================
#define G1_MT   128
#define G1_KC   32
#define G1_P    132   // xs pitch

__global__ __launch_bounds__(128) void k_gemm1(const float* __restrict__ x,
                                               const float* __restrict__ Wc,
                                               float* __restrict__ T, int N) {
  __shared__ float xs[G1_KC * G1_P];   // [kk][node]
  __shared__ float ws[G1_KC * 32];     // [kk][col]
  int t = threadIdx.x;
  int tm = t >> 3;   // 0..15 -> node group of 8
  int tn = t & 7;    // 0..7  -> col group of 4
  int rowBase = blockIdx.x * G1_MT;

  float acc[8][4];
  #pragma unroll
  for (int m = 0; m < 8; ++m)
    #pragma unroll
    for (int c = 0; c < 4; ++c) acc[m][c] = 0.f;

  for (int kc = 0; kc < F_IN; kc += G1_KC) {
    {
      int c = t & 31;          // k within chunk
      int rBase = t >> 5;      // 0..3
      int k = kc + c;
      bool kval = (k < F_IN);
      #pragma unroll
      for (int i = 0; i < 32; ++i) {
        int r = i * 4 + rBase;
        int gr = rowBase + r;
        float v = 0.f;
        if (kval && gr < N) v = x[(size_t)gr * F_IN + k];
        xs[c * G1_P + r] = v;
      }
      #pragma unroll
      for (int i = 0; i < 8; ++i) {
        int f = i * 128 + t;
        int wr = f >> 5, wc = f & 31;
        int kw = kc + wr;
        ws[wr * 32 + wc] = (kw < F_IN) ? Wc[kw * 32 + wc] : 0.f;
      }
    }
    __syncthreads();
    #pragma unroll
    for (int kk = 0; kk < G1_KC; ++kk) {
      const float* xp = &xs[kk * G1_P + tm * 8];
      float4 a0 = *(const float4*)(xp);
      float4 a1 = *(const float4*)(xp + 4);
      float4 b  = *(const float4*)(&ws[kk * 32 + tn * 4]);
      float am[8] = {a0.x, a0.y, a0.z, a0.w, a1.x, a1.y, a1.z, a1.w};
      float bn[4] = {b.x, b.y, b.z, b.w};
      #pragma unroll
      for (int m = 0; m < 8; ++m)
        #pragma unroll
        for (int c = 0; c < 4; ++c) acc[m][c] += am[m] * bn[c];
    }
    __syncthreads();
  }
  #pragma unroll
  for (int m = 0; m < 8; ++m) {
    int n = rowBase + tm * 8 + m;
    if (n < N) {
      float4 o = make_float4(acc[m][0], acc[m][1], acc[m][2], acc[m][3]);
      *(float4*)&T[(size_t)n * 32 + tn * 4] = o;
    }
  }
}

// ======================= small GEMM: h[N,16](f32) @ W[16,P](f32) -> T[N,P](f32) =======================
__global__ void k_gemm_small(const float* __restrict__ h, const float* __restrict__ W,
                             float* __restrict__ T, int N, int P) {
  int idx = blockIdx.x * 256 + threadIdx.x;
  int n = idx >> 5, c = idx & 31;
  if (n < N && c < P) {
    float acc = 0.f;
    #pragma unroll
    for (int k = 0; k < HD; ++k) acc += h[(size_t)n * HD + k] * W[k * P + c];
    T[(size_t)n * P + c] = acc;
  }
}

// ======================= gather + relu epilogue (layers 1,2) =======================
__global__ void k_gather_relu(const float* __restrict__ T, const int* __restrict__ off,
                              const int* __restrict__ cnt, const int* __restrict__ srow,
                              const float* __restrict__ dinv, const float* __restrict__ bias,
                              float* __restrict__ hout, int N) {
  int t = threadIdx.x;
  int j = t & 15, ln = t >> 4;
  int n = blockIdx.x * 16 + ln;
  if (n >= N) return;
  int s = off[n], c = cnt[n];
  float acc = 0.f;
  for (int p = s; p < s + c; ++p) {
    int r = srow[p];
    acc += dinv[r] * T[(size_t)r * 32 + j];
  }
  float v = dinv[n] * acc + T[(size_t)n * 32 + 16 + j] + bias[j];
  hout[(size_t)n * HD + j] = fmaxf(v, 0.f);
}

// ======================= gather + relu + log_softmax (layer 3, C=10, pitch 20), f32 out ===========
// ARMAConv applies relu INTERNALLY in every conv, including conv3: logits = relu(agg + h@w_root + b).
__global__ void k_gather_lsm(const float* __restrict__ T, const int* __restrict__ off,
                             const int* __restrict__ cnt, const int* __restrict__ srow,
                             const float* __restrict__ dinv, const float* __restrict__ b3,
                             float* __restrict__ out, int N) {
  int t = threadIdx.x;
  int j = t & 15, ln = t >> 4;
  int n = blockIdx.x * 16 + ln;
  bool act = (n < N) && (j < 10);
  float v = -1e30f;
  if (act) {
    int s = off[n], c = cnt[n];
    float acc = 0.f;
    for (int p = s; p < s + c; ++p) {
      int r = srow[p];
      acc += dinv[r] * T[(size_t)r * 20 + j];
    }
    v = dinv[n] * acc + T[(size_t)n * 20 + 10 + j] + b3[j];
    v = fmaxf(v, 0.f);   // <-- ARMAConv internal relu on conv3 output (the round-1/3 bug)
  }
  float m = v;
  #pragma unroll
  for (int mask = 8; mask >= 1; mask >>= 1) m = fmaxf(m, __shfl_xor(m, mask, 16));
  float e = act ? __expf(v - m) : 0.f;
  float sum = e;
  #pragma unroll
  for (int mask = 8; mask >= 1; mask >>= 1) sum += __shfl_xor(sum, mask, 16);
  if (act) out[(size_t)n * 10 + j] = (v - m) - __logf(sum);
}

// ======================= launch =======================
extern "C" void kernel_launch(void* const* d_in, const int* in_sizes, int n_in,
                              void* d_out, int out_size, void* d_ws, size_t ws_size,
                              hipStream_t stream) {
  const float* x    = (const float*)d_in[0];
  const int* eidx   = (const int*)d_in[1];
  const float* w1i  = (const float*)d_in[2];
  const float* w1r  = (const float*)d_in[3];
  const float* b1   = (const float*)d_in[4];
  const float* w2i  = (const float*)d_in[5];
  const float* w2r  = (const float*)d_in[6];
  const float* b2   = (const float*)d_in[7];
  const float* w3i  = (const float*)d_in[8];
  const float* w3r  = (const float*)d_in[9];
  const float* b3   = (const float*)d_in[10];
  float* out = (float*)d_out;

  const int N = in_sizes[0] / F_IN;     // 100000
  const int E = in_sizes[1] / 2;        // 3200000
  const int* row = eidx;
  const int* col = eidx + E;

  // workspace carve-up (256B aligned)
  char* p = (char*)d_ws;
  auto alloc = [&](size_t bytes) { void* r = (void*)p; p += (bytes + 255) & ~(size_t)255; return r; };
  int*   cnt  = (int*)alloc((size_t)N * 4);
  int*   off  = (int*)alloc((size_t)N * 4);
  int*   cur  = (int*)alloc((size_t)N * 4);
  float* dinv = (float*)alloc((size_t)N * 4);
  int*   bsum = (int*)alloc(1024);
  float* Wc   = (float*)alloc((size_t)F_IN * 32 * 4);
  float* W2c  = (float*)alloc((size_t)HD * 32 * 4);
  float* W3c  = (float*)alloc((size_t)HD * 20 * 4);
  int*   srow = (int*)alloc((size_t)E * 4);
  float* T    = (float*)alloc((size_t)N * 32 * 4);
  float* h    = (float*)alloc((size_t)N * HD * 4);

  const int nbE = (E + 255) / 256;
  const int nbScan = (N + 1023) / 1024;     // 98

  // edge sort (counting sort by col) + dinv
  hipMemsetAsync(cnt, 0, (size_t)N * 4, stream);
  k_hist <<<nbE, 256, 0, stream>>>(col, cnt, E);
  k_scan1<<<nbScan, 256, 0, stream>>>(cnt, off, bsum, N);
  k_scan2<<<1, 256, 0, stream>>>(bsum, nbScan);
  k_scan3<<<(N + 255) / 256, 256, 0, stream>>>(cnt, off, cur, dinv, bsum, N);
  k_build<<<nbE, 256, 0, stream>>>(row, col, cur, srow, E);

  // pack weights
  k_pack<<<(F_IN * 32 + 255) / 256, 256, 0, stream>>>(w1i, w1r, Wc, F_IN, 16);
  k_pack<<<(HD * 32 + 255) / 256, 256, 0, stream>>>(w2i, w2r, W2c, HD, 16);
  k_pack<<<(HD * 20 + 255) / 256, 256, 0, stream>>>(w3i, w3r, W3c, HD, 10);

  // layer 1
  k_gemm1<<<(N + G1_MT - 1) / G1_MT, 128, 0, stream>>>(x, Wc, T, N);
  k_gather_relu<<<(N + 15) / 16, 256, 0, stream>>>(T, off, cnt, srow, dinv, b1, h, N);
  // layer 2
  k_gemm_small<<<(N * 32 + 255) / 256, 256, 0, stream>>>(h, W2c, T, N, 32);
  k_gather_relu<<<(N + 15) / 16, 256, 0, stream>>>(T, off, cnt, srow, dinv, b2, h, N);
  // layer 3 + internal relu + log_softmax
  k_gemm_small<<<(N * 32 + 255) / 256, 256, 0, stream>>>(h, W3c, T, N, 20);
  k_gather_lsm<<<(N + 15) / 16, 256, 0, stream>>>(T, off, cnt, srow, dinv, b3, out, N);
}